// Round 5
// baseline (208.675 us; speedup 1.0000x reference)
//
#include <hip/hip_runtime.h>
#include <math.h>

#define L_SEQ 1024
#define DDIM  256
#define ADIM  128
#define NB    32

typedef __attribute__((ext_vector_type(8))) short bf16x8;
typedef __attribute__((ext_vector_type(4))) float f32x4;
typedef __attribute__((ext_vector_type(16))) float f32x16;

__device__ __forceinline__ ushort f2bf(float x) {      // fp32 -> bf16 RNE
    uint u = __builtin_bit_cast(uint, x);
    u = (u + 0x7FFFu + ((u >> 16) & 1u)) >> 16;
    return (ushort)u;
}
__device__ __forceinline__ float bf2f(ushort h) {
    uint u = ((uint)h) << 16;
    return __builtin_bit_cast(float, u);
}
__device__ __forceinline__ float tanh_fast(float x) {
    float ax = fabsf(x);
    float e  = __expf(ax * -2.0f);
    float r  = (1.0f - e) * __builtin_amdgcn_rcpf(1.0f + e);
    return copysignf(r, x);
}
// async global->LDS, 16B per lane; lds_dst wave-uniform, g_src per-lane
__device__ __forceinline__ void async_copy16(ushort* lds_dst, const ushort* g_src) {
    __builtin_amdgcn_global_load_lds(
        (const __attribute__((address_space(1))) unsigned int*)(g_src),
        (__attribute__((address_space(3))) unsigned int*)(lds_dst),
        16, 0, 0);
}

// ---------------------------------------------------------------------------
// fp32 -> bf16 elementwise convert (n multiple of 8)
// ---------------------------------------------------------------------------
__global__ __launch_bounds__(256) void cvt_bf16(const float* __restrict__ in,
                                                ushort* __restrict__ out, int n) {
    int i = (blockIdx.x * 256 + threadIdx.x) * 8;
    if (i >= n) return;
    float4 a = *reinterpret_cast<const float4*>(&in[i]);
    float4 b = *reinterpret_cast<const float4*>(&in[i + 4]);
    ushort4 lo = { f2bf(a.x), f2bf(a.y), f2bf(a.z), f2bf(a.w) };
    ushort4 hi = { f2bf(b.x), f2bf(b.y), f2bf(b.z), f2bf(b.w) };
    *reinterpret_cast<ushort4*>(&out[i]) = lo;
    *reinterpret_cast<ushort4*>(&out[i + 4]) = hi;
}

// ---------------------------------------------------------------------------
// Weight prep: w [256, N] fp32 -> WT_h/WT_l [N, 256] bf16 (transpose + split)
// ---------------------------------------------------------------------------
__global__ void wt_prep(const float* __restrict__ w, ushort* __restrict__ WTh,
                        ushort* __restrict__ WTl, int N) {
    int k = blockIdx.x;
    int n = threadIdx.x;
    float x = w[(size_t)k * N + n];
    ushort h = f2bf(x);
    WTh[(size_t)n * 256 + k] = h;
    WTl[(size_t)n * 256 + k] = f2bf(x - bf2f(h));
}

// ---------------------------------------------------------------------------
// Projection GEMM via MFMA + bf16 hi/lo split compensation (unchanged).
// ---------------------------------------------------------------------------
__global__ __launch_bounds__(256, 4) void proj_mfma(
        const float* __restrict__ A,
        const ushort* __restrict__ BTh, const ushort* __restrict__ BTl,
        ushort* __restrict__ C, int N) {
    __shared__ ushort Ash[64 * 32], Asl[64 * 32];
    __shared__ ushort Bsh[64 * 32], Bsl[64 * 32];

    const int tid  = threadIdx.x;
    const int lane = tid & 63;
    const int wid  = tid >> 6;
    const int l16  = lane & 15;
    const int lg   = lane >> 4;
    const int wrow = wid * 16;
    const int m0   = blockIdx.y * 64;
    const int n0   = blockIdx.x * 64;

    const int arow = tid >> 2;
    const int ac0  = (tid & 3) * 8;
    const int bn   = wid * 16 + (lane >> 2);
    const int bk   = (lane & 3) * 8;

    f32x4 acc[4];
    #pragma unroll
    for (int i = 0; i < 4; ++i) acc[i] = (f32x4){0.f, 0.f, 0.f, 0.f};

    for (int kc = 0; kc < 8; ++kc) {
        const int k0 = kc * 32;
        __syncthreads();
        const float* pa = A + (size_t)(m0 + arow) * 256 + k0 + ac0;
        float4 va = *reinterpret_cast<const float4*>(pa);
        float4 vb = *reinterpret_cast<const float4*>(pa + 4);
        float xs[8] = {va.x, va.y, va.z, va.w, vb.x, vb.y, vb.z, vb.w};
        ushort h[8], l[8];
        #pragma unroll
        for (int j = 0; j < 8; ++j) {
            h[j] = f2bf(xs[j]);
            l[j] = f2bf(xs[j] - bf2f(h[j]));
        }
        *reinterpret_cast<uint4*>(&Ash[arow * 32 + ac0]) = *reinterpret_cast<uint4*>(h);
        *reinterpret_cast<uint4*>(&Asl[arow * 32 + ac0]) = *reinterpret_cast<uint4*>(l);
        async_copy16(&Bsh[wid * 16 * 32], BTh + (size_t)(n0 + bn) * 256 + k0 + bk);
        async_copy16(&Bsl[wid * 16 * 32], BTl + (size_t)(n0 + bn) * 256 + k0 + bk);
        __syncthreads();

        bf16x8 ah = *reinterpret_cast<const bf16x8*>(&Ash[(wrow + l16) * 32 + lg * 8]);
        bf16x8 al = *reinterpret_cast<const bf16x8*>(&Asl[(wrow + l16) * 32 + lg * 8]);
        #pragma unroll
        for (int nf = 0; nf < 4; ++nf) {
            bf16x8 bh = *reinterpret_cast<const bf16x8*>(&Bsh[(nf * 16 + l16) * 32 + lg * 8]);
            bf16x8 bl = *reinterpret_cast<const bf16x8*>(&Bsl[(nf * 16 + l16) * 32 + lg * 8]);
            acc[nf] = __builtin_amdgcn_mfma_f32_16x16x32_bf16(ah, bh, acc[nf], 0, 0, 0);
            acc[nf] = __builtin_amdgcn_mfma_f32_16x16x32_bf16(ah, bl, acc[nf], 0, 0, 0);
            acc[nf] = __builtin_amdgcn_mfma_f32_16x16x32_bf16(al, bh, acc[nf], 0, 0, 0);
        }
    }

    #pragma unroll
    for (int nf = 0; nf < 4; ++nf)
        #pragma unroll
        for (int r = 0; r < 4; ++r)
            C[(size_t)(m0 + wrow + lg * 4 + r) * N + n0 + nf * 16 + l16] = f2bf(acc[nf][r]);
}

// ---------------------------------------------------------------------------
// Fused kernel, 32x32x16 MFMA version.
// Block = 4 waves; each wave owns 32 Q-rows (block tile = 128 rows).
// Key chunks of 32. LDS 36 KB. Q in registers (64 VGPR/lane).
// Grid 512 (XCD-swizzled): xcd=wg&7 owns 4 batches.
// ---------------------------------------------------------------------------
__global__ __launch_bounds__(256, 3) void fused_logits_mfma(
        const ushort* __restrict__ f1Wb, const ushort* __restrict__ f2b,
        const ushort* __restrict__ f1Wvb, const ushort* __restrict__ f2Wqb,
        const float* __restrict__ w_hv,  const float* __restrict__ w_hq,
        float* __restrict__ lo_v, float* __restrict__ lo_q) {
    __shared__ ushort KsU[32 * 256];   // swizzled: Ks[row*256+c] = K[row][c ^ ((row&15)<<3)]
    __shared__ ushort VtU[128 * 40];   // V^T [a][key], stride 40 (=80B, 16B-aligned rows)
    __shared__ ushort SsU[128 * 40];   // tanh(S) [qrow][key], stride 40

    const int tid  = threadIdx.x;
    const int lane = tid & 63;
    const int wid  = tid >> 6;
    const int l31  = lane & 31;
    const int h    = lane >> 5;
    const int h8   = h * 8;
    const int kxor = (l31 & 15) << 3;

    // XCD-aware decode: wg&7 = XCD; each XCD owns 4 complete batches
    const int wg   = blockIdx.x;
    const int xcd  = wg & 7;
    const int t    = wg >> 3;            // 0..63
    const int b    = xcd * 4 + (t >> 4);
    const int rem  = t & 15;
    const int z    = rem >> 3;
    const int r0   = (rem & 7) * 128;

    const ushort* Qb = z ? f2b   : f1Wb;
    const ushort* Kb = z ? f1Wb  : f2b;
    const ushort* Vg = z ? f1Wvb : f2Wqb;
    const ushort* Bg = z ? f2Wqb : f1Wvb;
    const float*  w  = z ? w_hq  : w_hv;
    float* logits    = z ? lo_q  : lo_v;

    // ---- Q fragments to registers: lane holds its row's k-half (128 elems)
    const int qrow = r0 + wid * 32 + l31;
    const ushort* qp = Qb + ((size_t)b * L_SEQ + qrow) * DDIM + h8;
    bf16x8 qf[16];
    #pragma unroll
    for (int st = 0; st < 16; ++st)
        qf[st] = *reinterpret_cast<const bf16x8*>(&qp[st * 16]);

    // per-lane swizzled source offsets for K staging
    int koff[4];
    #pragma unroll
    for (int it = 0; it < 4; ++it) {
        int row = wid * 8 + it * 2 + h;
        int col = (8 * l31) ^ ((row & 15) << 3);
        koff[it] = row * 256 + col;
    }

    f32x16 acc[4];
    #pragma unroll
    for (int i = 0; i < 4; ++i)
        #pragma unroll
        for (int j = 0; j < 16; ++j) acc[i][j] = 0.f;

    for (int c0 = 0; c0 < L_SEQ; c0 += 32) {
        __syncthreads();                    // prev chunk consumers done
        // ---- K chunk (32x256): async global->LDS, source pre-swizzled
        const ushort* gK = Kb + ((size_t)b * L_SEQ + c0) * DDIM;
        #pragma unroll
        for (int it = 0; it < 4; ++it)
            async_copy16(&KsU[(wid * 8 + it * 2) * 256], gK + koff[it]);

        // ---- V chunk (32x128) -> Vt[a][key] via coalesced column gather
        const ushort* gV = Vg + ((size_t)b * L_SEQ + c0) * ADIM;
        #pragma unroll
        for (int it = 0; it < 2; ++it) {
            int p = tid + it * 256;
            int a = p & 127, kg = p >> 7;
            const ushort* src = gV + (size_t)kg * 8 * ADIM + a;
            union { uint4 v4; ushort us[8]; } u;
            #pragma unroll
            for (int j = 0; j < 8; ++j) u.us[j] = src[(size_t)j * ADIM];
            *reinterpret_cast<uint4*>(&VtU[a * 40 + kg * 8]) = u.v4;
        }
        __syncthreads();                    // staging visible (vmcnt drained)

        // ---- S = Q . K^T : 32 rows x 32 keys, K=256 (16 k-steps)
        f32x16 s;
        #pragma unroll
        for (int j = 0; j < 16; ++j) s[j] = 0.f;
        #pragma unroll
        for (int st = 0; st < 16; ++st) {
            int e = l31 * 256 + ((st * 16 + h8) ^ kxor);
            bf16x8 kf = *reinterpret_cast<const bf16x8*>(&KsU[e]);
            s = __builtin_amdgcn_mfma_f32_32x32x16_bf16(qf[st], kf, s, 0, 0, 0);
        }
        // ---- tanh -> Ss (C layout: col=l31(key), row=(reg&3)+8*(reg>>2)+4h)
        #pragma unroll
        for (int reg = 0; reg < 16; ++reg) {
            int rowl = (reg & 3) + 8 * (reg >> 2) + 4 * h;
            SsU[(wid * 32 + rowl) * 40 + l31] = f2bf(tanh_fast(s[reg]));
        }
        // wave-local: this wave's 32 Ss rows are read only by itself
        asm volatile("s_waitcnt lgkmcnt(0)" ::: "memory");
        __builtin_amdgcn_sched_barrier(0);

        // ---- acc += S @ V : 32 rows x 128 cols, k = 32 keys (2 k-steps)
        #pragma unroll
        for (int kk = 0; kk < 2; ++kk) {
            bf16x8 sa = *reinterpret_cast<const bf16x8*>(
                &SsU[(wid * 32 + l31) * 40 + kk * 16 + h8]);
            #pragma unroll
            for (int nt = 0; nt < 4; ++nt) {
                bf16x8 vb = *reinterpret_cast<const bf16x8*>(
                    &VtU[(nt * 32 + l31) * 40 + kk * 16 + h8]);
                acc[nt] = __builtin_amdgcn_mfma_f32_32x32x16_bf16(sa, vb, acc[nt], 0, 0, 0);
            }
        }
    }

    // ---- epilogue: lane holds O[row][col=nt*32+l31], rows (reg&3)+8*(reg>>2)+4h
    float wv[4];
    #pragma unroll
    for (int nt = 0; nt < 4; ++nt) wv[nt] = w[nt * 32 + l31];
    const size_t bbase = ((size_t)b * L_SEQ + r0) * ADIM;
    #pragma unroll
    for (int reg = 0; reg < 16; ++reg) {
        int rowl = (reg & 3) + 8 * (reg >> 2) + 4 * h;
        int row  = wid * 32 + rowl;
        float p = 0.f;
        #pragma unroll
        for (int nt = 0; nt < 4; ++nt) {
            float bias = bf2f(Bg[bbase + (size_t)row * ADIM + nt * 32 + l31]);
            p = fmaf(tanh_fast(bias + acc[nt][reg]), wv[nt], p);
        }
        p += __shfl_xor(p, 1);
        p += __shfl_xor(p, 2);
        p += __shfl_xor(p, 4);
        p += __shfl_xor(p, 8);
        p += __shfl_xor(p, 16);
        if (l31 == 0) logits[(size_t)b * L_SEQ + r0 + row] = p;
    }
}

// ---------------------------------------------------------------------------
// Faithful masked softmax -> att weights (global).
// ---------------------------------------------------------------------------
__global__ __launch_bounds__(256) void attn_softmax(
        const float* __restrict__ lo_v, const float* __restrict__ lo_q,
        const int* __restrict__ mask1,  const int* __restrict__ mask2,
        float* __restrict__ att) {
    __shared__ float red[256];
    const int tid = threadIdx.x;
    const int b   = blockIdx.x;
    const int sel = blockIdx.y;
    const float* logits = sel ? lo_q : lo_v;
    const int*   mask   = sel ? mask2 : mask1;
    float* ao = att + ((size_t)sel * NB + b) * L_SEQ;

    float z[4], m[4];
    float lmax = -1e30f;
    #pragma unroll
    for (int i = 0; i < 4; ++i) {
        int l = i * 256 + tid;
        float lv = logits[(size_t)b * L_SEQ + l];
        m[i] = (float)mask[(size_t)b * L_SEQ + l];
        z[i] = lv * m[i];
        lmax = fmaxf(lmax, z[i]);
    }
    red[tid] = lmax; __syncthreads();
    for (int s = 128; s > 0; s >>= 1) {
        if (tid < s) red[tid] = fmaxf(red[tid], red[tid + s]);
        __syncthreads();
    }
    const float mx = red[0];
    __syncthreads();

    float p[4], lsum = 0.f;
    #pragma unroll
    for (int i = 0; i < 4; ++i) { p[i] = expf(z[i] - mx); lsum += p[i]; }
    red[tid] = lsum; __syncthreads();
    for (int s = 128; s > 0; s >>= 1) {
        if (tid < s) red[tid] += red[tid + s];
        __syncthreads();
    }
    const float Z = red[0];
    __syncthreads();

    float r[4], rsum = 0.f;
    #pragma unroll
    for (int i = 0; i < 4; ++i) { r[i] = (p[i] / Z) * m[i]; rsum += r[i]; }
    red[tid] = rsum; __syncthreads();
    for (int s = 128; s > 0; s >>= 1) {
        if (tid < s) red[tid] += red[tid + s];
        __syncthreads();
    }
    const float denom = red[0] + 1e-13f;

    #pragma unroll
    for (int i = 0; i < 4; ++i) ao[i * 256 + tid] = r[i] / denom;
}

// ---------------------------------------------------------------------------
// Split-K attention-weighted row sum: partial[z][sel][b][d] over 128 l each.
// ---------------------------------------------------------------------------
__global__ __launch_bounds__(256) void wsum_partial(
        const float* __restrict__ att, const float* __restrict__ f1,
        const float* __restrict__ f2,  float* __restrict__ partial) {
    __shared__ float a_s[128];
    const int tid = threadIdx.x;
    const int b   = blockIdx.x;
    const int sel = blockIdx.y;
    const int z   = blockIdx.z;
    const int l0  = z * 128;
    const float* ap = att + ((size_t)sel * NB + b) * L_SEQ + l0;
    if (tid < 128) a_s[tid] = ap[tid];
    __syncthreads();
    const float* f = sel ? f2 : f1;
    const float* fb = f + ((size_t)b * L_SEQ + l0) * DDIM + tid;
    float acc = 0.f;
    #pragma unroll 4
    for (int j = 0; j < 128; ++j)
        acc = fmaf(a_s[j], fb[(size_t)j * DDIM], acc);
    partial[(((size_t)z * 2 + sel) * NB + b) * DDIM + tid] = acc;
}

__global__ __launch_bounds__(256) void wsum_reduce(
        const float* __restrict__ partial, float* __restrict__ out) {
    const int tid = threadIdx.x;
    const int sb  = blockIdx.x;          // sel*NB + b
    float s = 0.f;
    #pragma unroll
    for (int zz = 0; zz < 8; ++zz)
        s += partial[((size_t)zz * 64 + sb) * DDIM + tid];
    out[(size_t)sb * DDIM + tid] = s;
}

// ---------------------------------------------------------------------------
extern "C" void kernel_launch(void* const* d_in, const int* in_sizes, int n_in,
                              void* d_out, int out_size, void* d_ws, size_t ws_size,
                              hipStream_t stream) {
    const float* f1    = (const float*)d_in[0];
    const float* f2    = (const float*)d_in[1];
    const int*   mask1 = (const int*)d_in[2];
    const int*   mask2 = (const int*)d_in[3];
    const float* W     = (const float*)d_in[4];
    const float* Wv    = (const float*)d_in[5];
    const float* Wq    = (const float*)d_in[6];
    const float* w_hv  = (const float*)d_in[7];
    const float* w_hq  = (const float*)d_in[8];
    float* out = (float*)d_out;

    // workspace layout (ushort units) ~50 MB total
    ushort* f2b   = (ushort*)d_ws;              // [32,1024,256] bf16
    ushort* f1Wb  = f2b   + 8388608;            // [32,1024,256] bf16
    ushort* f1Wvb = f1Wb  + 8388608;            // [32,1024,128] bf16
    ushort* f2Wqb = f1Wvb + 4194304;            // [32,1024,128] bf16
    ushort* WTh   = f2Wqb + 4194304;            // [256,256]
    ushort* WTl   = WTh   + 65536;
    ushort* WvTh  = WTl   + 65536;              // [128,256]
    ushort* WvTl  = WvTh  + 32768;
    ushort* WqTh  = WvTl  + 32768;
    ushort* WqTl  = WqTh  + 32768;
    float*  lo_v  = (float*)(WqTl + 32768);     // [32,1024]
    float*  lo_q  = lo_v + 32768;               // [32,1024]
    float*  att   = lo_q + 32768;               // [2,32,1024]
    float*  part  = att  + 65536;               // [8,2,32,256]

    const int M = NB * L_SEQ;                   // 32768

    wt_prep<<<256, 256, 0, stream>>>(W,  WTh,  WTl,  256);
    wt_prep<<<256, 128, 0, stream>>>(Wv, WvTh, WvTl, 128);
    wt_prep<<<256, 128, 0, stream>>>(Wq, WqTh, WqTl, 128);
    cvt_bf16<<<4096, 256, 0, stream>>>(f2, f2b, 8388608);

    proj_mfma<<<dim3(4, 512), 256, 0, stream>>>(f1, WTh,  WTl,  f1Wb,  256);
    proj_mfma<<<dim3(2, 512), 256, 0, stream>>>(f1, WvTh, WvTl, f1Wvb, 128);
    proj_mfma<<<dim3(2, 512), 256, 0, stream>>>(f2, WqTh, WqTl, f2Wqb, 128);

    fused_logits_mfma<<<512, 256, 0, stream>>>(
        f1Wb, f2b, f1Wvb, f2Wqb, w_hv, w_hq, lo_v, lo_q);

    attn_softmax<<<dim3(NB, 2), 256, 0, stream>>>(lo_v, lo_q, mask1, mask2, att);
    wsum_partial<<<dim3(NB, 2, 8), 256, 0, stream>>>(att, f1, f2, part);
    wsum_reduce<<<64, 256, 0, stream>>>(part, out);
}

// Round 6
// 175.811 us; speedup vs baseline: 1.1869x; 1.1869x over previous
//
#include <hip/hip_runtime.h>
#include <math.h>

#define L_SEQ 1024
#define DDIM  256
#define ADIM  128
#define NB    32

typedef __attribute__((ext_vector_type(8))) short bf16x8;
typedef __attribute__((ext_vector_type(4))) float f32x4;
typedef __attribute__((ext_vector_type(16))) float f32x16;

__device__ __forceinline__ ushort f2bf(float x) {      // fp32 -> bf16 RNE
    uint u = __builtin_bit_cast(uint, x);
    u = (u + 0x7FFFu + ((u >> 16) & 1u)) >> 16;
    return (ushort)u;
}
__device__ __forceinline__ float bf2f(ushort h) {
    uint u = ((uint)h) << 16;
    return __builtin_bit_cast(float, u);
}
__device__ __forceinline__ float tanh_fast(float x) {
    float ax = fabsf(x);
    float e  = __expf(ax * -2.0f);
    float r  = (1.0f - e) * __builtin_amdgcn_rcpf(1.0f + e);
    return copysignf(r, x);
}
// async global->LDS, 16B per lane; lds_dst wave-uniform, g_src per-lane
__device__ __forceinline__ void async_copy16(ushort* lds_dst, const ushort* g_src) {
    __builtin_amdgcn_global_load_lds(
        (const __attribute__((address_space(1))) unsigned int*)(g_src),
        (__attribute__((address_space(3))) unsigned int*)(lds_dst),
        16, 0, 0);
}

// ---------------------------------------------------------------------------
// fp32 -> bf16 elementwise convert (n multiple of 8)
// ---------------------------------------------------------------------------
__global__ __launch_bounds__(256) void cvt_bf16(const float* __restrict__ in,
                                                ushort* __restrict__ out, int n) {
    int i = (blockIdx.x * 256 + threadIdx.x) * 8;
    if (i >= n) return;
    float4 a = *reinterpret_cast<const float4*>(&in[i]);
    float4 b = *reinterpret_cast<const float4*>(&in[i + 4]);
    ushort4 lo = { f2bf(a.x), f2bf(a.y), f2bf(a.z), f2bf(a.w) };
    ushort4 hi = { f2bf(b.x), f2bf(b.y), f2bf(b.z), f2bf(b.w) };
    *reinterpret_cast<ushort4*>(&out[i]) = lo;
    *reinterpret_cast<ushort4*>(&out[i + 4]) = hi;
}

// ---------------------------------------------------------------------------
// Weight prep: w [256, N] fp32 -> WT_h/WT_l [N, 256] bf16 (transpose + split)
// ---------------------------------------------------------------------------
__global__ void wt_prep(const float* __restrict__ w, ushort* __restrict__ WTh,
                        ushort* __restrict__ WTl, int N) {
    int k = blockIdx.x;
    int n = threadIdx.x;
    float x = w[(size_t)k * N + n];
    ushort h = f2bf(x);
    WTh[(size_t)n * 256 + k] = h;
    WTl[(size_t)n * 256 + k] = f2bf(x - bf2f(h));
}

// ---------------------------------------------------------------------------
// Projection GEMM via MFMA + bf16 hi/lo split compensation (unchanged).
// ---------------------------------------------------------------------------
__global__ __launch_bounds__(256, 4) void proj_mfma(
        const float* __restrict__ A,
        const ushort* __restrict__ BTh, const ushort* __restrict__ BTl,
        ushort* __restrict__ C, int N) {
    __shared__ ushort Ash[64 * 32], Asl[64 * 32];
    __shared__ ushort Bsh[64 * 32], Bsl[64 * 32];

    const int tid  = threadIdx.x;
    const int lane = tid & 63;
    const int wid  = tid >> 6;
    const int l16  = lane & 15;
    const int lg   = lane >> 4;
    const int wrow = wid * 16;
    const int m0   = blockIdx.y * 64;
    const int n0   = blockIdx.x * 64;

    const int arow = tid >> 2;
    const int ac0  = (tid & 3) * 8;
    const int bn   = wid * 16 + (lane >> 2);
    const int bk   = (lane & 3) * 8;

    f32x4 acc[4];
    #pragma unroll
    for (int i = 0; i < 4; ++i) acc[i] = (f32x4){0.f, 0.f, 0.f, 0.f};

    for (int kc = 0; kc < 8; ++kc) {
        const int k0 = kc * 32;
        __syncthreads();
        const float* pa = A + (size_t)(m0 + arow) * 256 + k0 + ac0;
        float4 va = *reinterpret_cast<const float4*>(pa);
        float4 vb = *reinterpret_cast<const float4*>(pa + 4);
        float xs[8] = {va.x, va.y, va.z, va.w, vb.x, vb.y, vb.z, vb.w};
        ushort h[8], l[8];
        #pragma unroll
        for (int j = 0; j < 8; ++j) {
            h[j] = f2bf(xs[j]);
            l[j] = f2bf(xs[j] - bf2f(h[j]));
        }
        *reinterpret_cast<uint4*>(&Ash[arow * 32 + ac0]) = *reinterpret_cast<uint4*>(h);
        *reinterpret_cast<uint4*>(&Asl[arow * 32 + ac0]) = *reinterpret_cast<uint4*>(l);
        async_copy16(&Bsh[wid * 16 * 32], BTh + (size_t)(n0 + bn) * 256 + k0 + bk);
        async_copy16(&Bsl[wid * 16 * 32], BTl + (size_t)(n0 + bn) * 256 + k0 + bk);
        __syncthreads();

        bf16x8 ah = *reinterpret_cast<const bf16x8*>(&Ash[(wrow + l16) * 32 + lg * 8]);
        bf16x8 al = *reinterpret_cast<const bf16x8*>(&Asl[(wrow + l16) * 32 + lg * 8]);
        #pragma unroll
        for (int nf = 0; nf < 4; ++nf) {
            bf16x8 bh = *reinterpret_cast<const bf16x8*>(&Bsh[(nf * 16 + l16) * 32 + lg * 8]);
            bf16x8 bl = *reinterpret_cast<const bf16x8*>(&Bsl[(nf * 16 + l16) * 32 + lg * 8]);
            acc[nf] = __builtin_amdgcn_mfma_f32_16x16x32_bf16(ah, bh, acc[nf], 0, 0, 0);
            acc[nf] = __builtin_amdgcn_mfma_f32_16x16x32_bf16(ah, bl, acc[nf], 0, 0, 0);
            acc[nf] = __builtin_amdgcn_mfma_f32_16x16x32_bf16(al, bh, acc[nf], 0, 0, 0);
        }
    }

    #pragma unroll
    for (int nf = 0; nf < 4; ++nf)
        #pragma unroll
        for (int r = 0; r < 4; ++r)
            C[(size_t)(m0 + wrow + lg * 4 + r) * N + n0 + nf * 16 + l16] = f2bf(acc[nf][r]);
}

// ---------------------------------------------------------------------------
// Fused kernel, 32x32x16 MFMA, double-buffered K/V pipeline.
// Block = 4 waves; wave owns 32 Q-rows (block tile = 128 rows); key chunks 32.
// LDS 63.5 KB -> 2 blocks/CU (grid 512 = exactly 2/CU).
// One barrier per chunk; K DMA + V gather issued before compute (latency
// hidden); Ss is wave-private (no barrier).
// ---------------------------------------------------------------------------
__global__ __launch_bounds__(256, 2) void fused_logits_mfma(
        const ushort* __restrict__ f1Wb, const ushort* __restrict__ f2b,
        const ushort* __restrict__ f1Wvb, const ushort* __restrict__ f2Wqb,
        const float* __restrict__ w_hv,  const float* __restrict__ w_hq,
        float* __restrict__ lo_v, float* __restrict__ lo_q) {
    __shared__ ushort KsU[2 * 32 * 256];  // swizzled: [row*256 + (c ^ ((row&15)<<3))]
    __shared__ ushort VtU[2 * 128 * 40];  // V^T [a][key], stride 40
    __shared__ ushort SsU[128 * 40];      // tanh(S) [qrow][key], wave-private rows

    const int tid  = threadIdx.x;
    const int lane = tid & 63;
    const int wid  = tid >> 6;
    const int l31  = lane & 31;
    const int h    = lane >> 5;
    const int h8   = h * 8;
    const int kxor = (l31 & 15) << 3;

    // XCD-aware decode: wg&7 = XCD; each XCD owns 4 complete batches
    const int wg   = blockIdx.x;
    const int xcd  = wg & 7;
    const int t    = wg >> 3;            // 0..63
    const int b    = xcd * 4 + (t >> 4);
    const int rem  = t & 15;
    const int z    = rem >> 3;
    const int r0   = (rem & 7) * 128;

    const ushort* Qb = z ? f2b   : f1Wb;
    const ushort* Kb = z ? f1Wb  : f2b;
    const ushort* Vg = z ? f1Wvb : f2Wqb;
    const ushort* Bg = z ? f2Wqb : f1Wvb;
    const float*  w  = z ? w_hq  : w_hv;
    float* logits    = z ? lo_q  : lo_v;

    // ---- Q fragments to registers: lane holds its row's k-half (128 elems)
    const int qrow = r0 + wid * 32 + l31;
    const ushort* qp = Qb + ((size_t)b * L_SEQ + qrow) * DDIM + h8;
    bf16x8 qf[16];
    #pragma unroll
    for (int st = 0; st < 16; ++st)
        qf[st] = *reinterpret_cast<const bf16x8*>(&qp[st * 16]);

    // per-lane swizzled source offsets for K staging
    int koff[4];
    #pragma unroll
    for (int it = 0; it < 4; ++it) {
        int row = wid * 8 + it * 2 + h;
        int col = (8 * l31) ^ ((row & 15) << 3);
        koff[it] = row * 256 + col;
    }
    // V gather coords (per thread, two slots)
    const int va0 = tid & 127,          vk0 = tid >> 7;
    const int va1 = (tid + 256) & 127,  vk1 = (tid + 256) >> 7;

    f32x16 acc[4];
    #pragma unroll
    for (int i = 0; i < 4; ++i)
        #pragma unroll
        for (int j = 0; j < 16; ++j) acc[i][j] = 0.f;

    uint4 vr0, vr1;

    // ---- prologue: stage chunk 0 into buffer 0
    {
        const ushort* gK = Kb + (size_t)b * L_SEQ * DDIM;
        #pragma unroll
        for (int it = 0; it < 4; ++it)
            async_copy16(&KsU[(wid * 8 + it * 2) * 256], gK + koff[it]);
        const ushort* gV = Vg + (size_t)b * L_SEQ * ADIM;
        union { uint4 v4; ushort us[8]; } u;
        const ushort* s0 = gV + (size_t)vk0 * 8 * ADIM + va0;
        #pragma unroll
        for (int j = 0; j < 8; ++j) u.us[j] = s0[(size_t)j * ADIM];
        vr0 = u.v4;
        const ushort* s1 = gV + (size_t)vk1 * 8 * ADIM + va1;
        #pragma unroll
        for (int j = 0; j < 8; ++j) u.us[j] = s1[(size_t)j * ADIM];
        vr1 = u.v4;
        *reinterpret_cast<uint4*>(&VtU[va0 * 40 + vk0 * 8]) = vr0;
        *reinterpret_cast<uint4*>(&VtU[va1 * 40 + vk1 * 8]) = vr1;
    }
    __syncthreads();   // drains vmcnt (K DMA) + lgkm (V writes)

    int cur = 0;
    for (int c0 = 0; c0 < L_SEQ; c0 += 32) {
        const int nxt = cur ^ 1;
        const ushort* Kc = &KsU[cur * (32 * 256)];
        const ushort* Vc = &VtU[cur * (128 * 40)];
        const bool more = (c0 + 32 < L_SEQ);

        // ---- issue next chunk's loads (latency hidden under compute)
        if (more) {
            ushort* Kn = &KsU[nxt * (32 * 256)];
            const ushort* gK = Kb + ((size_t)b * L_SEQ + c0 + 32) * DDIM;
            #pragma unroll
            for (int it = 0; it < 4; ++it)
                async_copy16(&Kn[(wid * 8 + it * 2) * 256], gK + koff[it]);
            const ushort* gV = Vg + ((size_t)b * L_SEQ + c0 + 32) * ADIM;
            union { uint4 v4; ushort us[8]; } u;
            const ushort* s0 = gV + (size_t)vk0 * 8 * ADIM + va0;
            #pragma unroll
            for (int j = 0; j < 8; ++j) u.us[j] = s0[(size_t)j * ADIM];
            vr0 = u.v4;
            const ushort* s1 = gV + (size_t)vk1 * 8 * ADIM + va1;
            #pragma unroll
            for (int j = 0; j < 8; ++j) u.us[j] = s1[(size_t)j * ADIM];
            vr1 = u.v4;
        }

        // ---- S = Q . K^T : 32 rows x 32 keys, K=256 (two independent chains)
        f32x16 sA, sB;
        #pragma unroll
        for (int j = 0; j < 16; ++j) { sA[j] = 0.f; sB[j] = 0.f; }
        #pragma unroll
        for (int st = 0; st < 8; ++st) {
            bf16x8 k0 = *reinterpret_cast<const bf16x8*>(
                &Kc[l31 * 256 + (((2 * st) * 16 + h8) ^ kxor)]);
            bf16x8 k1 = *reinterpret_cast<const bf16x8*>(
                &Kc[l31 * 256 + (((2 * st + 1) * 16 + h8) ^ kxor)]);
            sA = __builtin_amdgcn_mfma_f32_32x32x16_bf16(qf[2 * st],     k0, sA, 0, 0, 0);
            sB = __builtin_amdgcn_mfma_f32_32x32x16_bf16(qf[2 * st + 1], k1, sB, 0, 0, 0);
        }
        // ---- tanh -> Ss (wave-private rows; C layout: col=l31, row=(reg&3)+8*(reg>>2)+4h)
        #pragma unroll
        for (int reg = 0; reg < 16; ++reg) {
            int rowl = (reg & 3) + 8 * (reg >> 2) + 4 * h;
            SsU[(wid * 32 + rowl) * 40 + l31] = f2bf(tanh_fast(sA[reg] + sB[reg]));
        }
        asm volatile("s_waitcnt lgkmcnt(0)" ::: "memory");
        __builtin_amdgcn_sched_barrier(0);

        // ---- acc += S @ V : 32 rows x 128 cols, k = 32 keys
        #pragma unroll
        for (int kk = 0; kk < 2; ++kk) {
            bf16x8 sa = *reinterpret_cast<const bf16x8*>(
                &SsU[(wid * 32 + l31) * 40 + kk * 16 + h8]);
            #pragma unroll
            for (int nt = 0; nt < 4; ++nt) {
                bf16x8 vb = *reinterpret_cast<const bf16x8*>(
                    &Vc[(nt * 32 + l31) * 40 + kk * 16 + h8]);
                acc[nt] = __builtin_amdgcn_mfma_f32_32x32x16_bf16(sa, vb, acc[nt], 0, 0, 0);
            }
        }

        // ---- land next chunk's V into LDS, then one barrier
        if (more) {
            ushort* Vn = &VtU[nxt * (128 * 40)];
            *reinterpret_cast<uint4*>(&Vn[va0 * 40 + vk0 * 8]) = vr0;
            *reinterpret_cast<uint4*>(&Vn[va1 * 40 + vk1 * 8]) = vr1;
        }
        __syncthreads();   // implicit vmcnt(0)+lgkmcnt(0): K DMA + V writes visible
        cur = nxt;
    }

    // ---- epilogue: lane holds O[row][col=nt*32+l31], rows (reg&3)+8*(reg>>2)+4h
    float wv[4];
    #pragma unroll
    for (int nt = 0; nt < 4; ++nt) wv[nt] = w[nt * 32 + l31];
    const size_t bbase = ((size_t)b * L_SEQ + r0) * ADIM;
    #pragma unroll
    for (int reg = 0; reg < 16; ++reg) {
        int rowl = (reg & 3) + 8 * (reg >> 2) + 4 * h;
        int row  = wid * 32 + rowl;
        float p = 0.f;
        #pragma unroll
        for (int nt = 0; nt < 4; ++nt) {
            float bias = bf2f(Bg[bbase + (size_t)row * ADIM + nt * 32 + l31]);
            p = fmaf(tanh_fast(bias + acc[nt][reg]), wv[nt], p);
        }
        p += __shfl_xor(p, 1);
        p += __shfl_xor(p, 2);
        p += __shfl_xor(p, 4);
        p += __shfl_xor(p, 8);
        p += __shfl_xor(p, 16);
        if (l31 == 0) logits[(size_t)b * L_SEQ + r0 + row] = p;
    }
}

// ---------------------------------------------------------------------------
// Faithful masked softmax -> att weights (global).
// ---------------------------------------------------------------------------
__global__ __launch_bounds__(256) void attn_softmax(
        const float* __restrict__ lo_v, const float* __restrict__ lo_q,
        const int* __restrict__ mask1,  const int* __restrict__ mask2,
        float* __restrict__ att) {
    __shared__ float red[256];
    const int tid = threadIdx.x;
    const int b   = blockIdx.x;
    const int sel = blockIdx.y;
    const float* logits = sel ? lo_q : lo_v;
    const int*   mask   = sel ? mask2 : mask1;
    float* ao = att + ((size_t)sel * NB + b) * L_SEQ;

    float z[4], m[4];
    float lmax = -1e30f;
    #pragma unroll
    for (int i = 0; i < 4; ++i) {
        int l = i * 256 + tid;
        float lv = logits[(size_t)b * L_SEQ + l];
        m[i] = (float)mask[(size_t)b * L_SEQ + l];
        z[i] = lv * m[i];
        lmax = fmaxf(lmax, z[i]);
    }
    red[tid] = lmax; __syncthreads();
    for (int s = 128; s > 0; s >>= 1) {
        if (tid < s) red[tid] = fmaxf(red[tid], red[tid + s]);
        __syncthreads();
    }
    const float mx = red[0];
    __syncthreads();

    float p[4], lsum = 0.f;
    #pragma unroll
    for (int i = 0; i < 4; ++i) { p[i] = expf(z[i] - mx); lsum += p[i]; }
    red[tid] = lsum; __syncthreads();
    for (int s = 128; s > 0; s >>= 1) {
        if (tid < s) red[tid] += red[tid + s];
        __syncthreads();
    }
    const float Z = red[0];
    __syncthreads();

    float r[4], rsum = 0.f;
    #pragma unroll
    for (int i = 0; i < 4; ++i) { r[i] = (p[i] / Z) * m[i]; rsum += r[i]; }
    red[tid] = rsum; __syncthreads();
    for (int s = 128; s > 0; s >>= 1) {
        if (tid < s) red[tid] += red[tid + s];
        __syncthreads();
    }
    const float denom = red[0] + 1e-13f;

    #pragma unroll
    for (int i = 0; i < 4; ++i) ao[i * 256 + tid] = r[i] / denom;
}

// ---------------------------------------------------------------------------
// Split-K attention-weighted row sum: partial[z][sel][b][d] over 128 l each.
// ---------------------------------------------------------------------------
__global__ __launch_bounds__(256) void wsum_partial(
        const float* __restrict__ att, const float* __restrict__ f1,
        const float* __restrict__ f2,  float* __restrict__ partial) {
    __shared__ float a_s[128];
    const int tid = threadIdx.x;
    const int b   = blockIdx.x;
    const int sel = blockIdx.y;
    const int z   = blockIdx.z;
    const int l0  = z * 128;
    const float* ap = att + ((size_t)sel * NB + b) * L_SEQ + l0;
    if (tid < 128) a_s[tid] = ap[tid];
    __syncthreads();
    const float* f = sel ? f2 : f1;
    const float* fb = f + ((size_t)b * L_SEQ + l0) * DDIM + tid;
    float acc = 0.f;
    #pragma unroll 4
    for (int j = 0; j < 128; ++j)
        acc = fmaf(a_s[j], fb[(size_t)j * DDIM], acc);
    partial[(((size_t)z * 2 + sel) * NB + b) * DDIM + tid] = acc;
}

__global__ __launch_bounds__(256) void wsum_reduce(
        const float* __restrict__ partial, float* __restrict__ out) {
    const int tid = threadIdx.x;
    const int sb  = blockIdx.x;          // sel*NB + b
    float s = 0.f;
    #pragma unroll
    for (int zz = 0; zz < 8; ++zz)
        s += partial[((size_t)zz * 64 + sb) * DDIM + tid];
    out[(size_t)sb * DDIM + tid] = s;
}

// ---------------------------------------------------------------------------
extern "C" void kernel_launch(void* const* d_in, const int* in_sizes, int n_in,
                              void* d_out, int out_size, void* d_ws, size_t ws_size,
                              hipStream_t stream) {
    const float* f1    = (const float*)d_in[0];
    const float* f2    = (const float*)d_in[1];
    const int*   mask1 = (const int*)d_in[2];
    const int*   mask2 = (const int*)d_in[3];
    const float* W     = (const float*)d_in[4];
    const float* Wv    = (const float*)d_in[5];
    const float* Wq    = (const float*)d_in[6];
    const float* w_hv  = (const float*)d_in[7];
    const float* w_hq  = (const float*)d_in[8];
    float* out = (float*)d_out;

    // workspace layout (ushort units) ~50 MB total
    ushort* f2b   = (ushort*)d_ws;              // [32,1024,256] bf16
    ushort* f1Wb  = f2b   + 8388608;            // [32,1024,256] bf16
    ushort* f1Wvb = f1Wb  + 8388608;            // [32,1024,128] bf16
    ushort* f2Wqb = f1Wvb + 4194304;            // [32,1024,128] bf16
    ushort* WTh   = f2Wqb + 4194304;            // [256,256]
    ushort* WTl   = WTh   + 65536;
    ushort* WvTh  = WTl   + 65536;              // [128,256]
    ushort* WvTl  = WvTh  + 32768;
    ushort* WqTh  = WvTl  + 32768;
    ushort* WqTl  = WqTh  + 32768;
    float*  lo_v  = (float*)(WqTl + 32768);     // [32,1024]
    float*  lo_q  = lo_v + 32768;               // [32,1024]
    float*  att   = lo_q + 32768;               // [2,32,1024]
    float*  part  = att  + 65536;               // [8,2,32,256]

    wt_prep<<<256, 256, 0, stream>>>(W,  WTh,  WTl,  256);
    wt_prep<<<256, 128, 0, stream>>>(Wv, WvTh, WvTl, 128);
    wt_prep<<<256, 128, 0, stream>>>(Wq, WqTh, WqTl, 128);
    cvt_bf16<<<4096, 256, 0, stream>>>(f2, f2b, 8388608);

    proj_mfma<<<dim3(4, 512), 256, 0, stream>>>(f1, WTh,  WTl,  f1Wb,  256);
    proj_mfma<<<dim3(2, 512), 256, 0, stream>>>(f1, WvTh, WvTl, f1Wvb, 128);
    proj_mfma<<<dim3(2, 512), 256, 0, stream>>>(f2, WqTh, WqTl, f2Wqb, 128);

    fused_logits_mfma<<<512, 256, 0, stream>>>(
        f1Wb, f2b, f1Wvb, f2Wqb, w_hv, w_hq, lo_v, lo_q);

    attn_softmax<<<dim3(NB, 2), 256, 0, stream>>>(lo_v, lo_q, mask1, mask2, att);
    wsum_partial<<<dim3(NB, 2, 8), 256, 0, stream>>>(att, f1, f2, part);
    wsum_reduce<<<64, 256, 0, stream>>>(part, out);
}